// Round 1
// 182.231 us; speedup vs baseline: 1.0614x; 1.0614x over previous
//
#include <hip/hip_runtime.h>
#include <stdint.h>

#define NL     8192
#define NH     32768
#define FDIM   128
#define KSEL   32
#define CHUNK  1024
#define NCHUNK (NL / CHUNK)
#define QPW    8                 // queries per wave
#define NWAVES 4
#define BLOCK  (NWAVES * 64)
#define QPB    (NWAVES * QPW)    // 32 queries per block
#define BUFCAP 128

typedef float f32x2 __attribute__((ext_vector_type(2)));

__device__ __forceinline__ int imin(int a, int b) { return a < b ? a : b; }
__device__ __forceinline__ int imax(int a, int b) { return a > b ? a : b; }

// Packed fp32 FMA, broadcasting src1's LOW register into both halves:
// d.lo = s0.lo * s1.lo + s2.lo ; d.hi = s0.hi * s1.lo + s2.hi
__device__ __forceinline__ f32x2 pk_fma_lo(f32x2 s0, f32x2 s1, f32x2 s2) {
    f32x2 d;
    asm("v_pk_fma_f32 %0, %1, %2, %3 op_sel:[0,0,0] op_sel_hi:[1,0,1]"
        : "=v"(d) : "v"(s0), "v"(s1), "v"(s2));
    return d;
}
// Packed fp32 FMA, broadcasting src1's HIGH register into both halves.
__device__ __forceinline__ f32x2 pk_fma_hi(f32x2 s0, f32x2 s1, f32x2 s2) {
    f32x2 d;
    asm("v_pk_fma_f32 %0, %1, %2, %3 op_sel:[0,1,0] op_sel_hi:[1,1,1]"
        : "=v"(d) : "v"(s0), "v"(s1), "v"(s2));
    return d;
}

__global__ __launch_bounds__(BLOCK, 4)
void knn_interp_kernel(const float* __restrict__ x,
                       const float* __restrict__ pos_l,
                       const float* __restrict__ pos_h,
                       float* __restrict__ out)
{
    // SoA pair-packed candidate staging: element i holds candidates (2i, 2i+1)
    __shared__ f32x2    s_x[CHUNK/2], s_y[CHUNK/2], s_z[CHUNK/2], s_w[CHUNK/2]; // 16 KB
    __shared__ uint16_t s_idx[QPB][BUFCAP];     // 8 KB candidate index buffers
    __shared__ uint32_t s_cnt[QPB];
    __shared__ float    s_wd2[QPB][KSEL];       // winner d2 (fp32 from fp64)
    __shared__ uint16_t s_widx[QPB][KSEL];      // winner indices

    const int tid   = threadIdx.x;
    const int lane  = tid & 63;
    const int wid   = tid >> 6;
    const int qbase = blockIdx.x * QPB + wid * QPW;

    // per-query-pair packed params: hxq[j] = (-2*ax(2j), -2*ax(2j+1)), etc.
    // Sweeps rank by s = |l|^2 - 2 h.l  (= d2 - |h|^2, constant shift per query)
    f32x2 hxq[QPW/2], hyq[QPW/2], hzq[QPW/2];
#pragma unroll
    for (int j = 0; j < QPW/2; ++j) {
        const float a0x = pos_h[(size_t)(qbase + 2*j    ) * 3 + 0];
        const float a0y = pos_h[(size_t)(qbase + 2*j    ) * 3 + 1];
        const float a0z = pos_h[(size_t)(qbase + 2*j    ) * 3 + 2];
        const float a1x = pos_h[(size_t)(qbase + 2*j + 1) * 3 + 0];
        const float a1y = pos_h[(size_t)(qbase + 2*j + 1) * 3 + 1];
        const float a1z = pos_h[(size_t)(qbase + 2*j + 1) * 3 + 2];
        hxq[j] = (f32x2){-2.0f * a0x, -2.0f * a1x};
        hyq[j] = (f32x2){-2.0f * a0y, -2.0f * a1y};
        hzq[j] = (f32x2){-2.0f * a0z, -2.0f * a1z};
    }

    f32x2 rminp[QPW];
#pragma unroll
    for (int q = 0; q < QPW; ++q) rminp[q] = (f32x2){INFINITY, INFINITY};

    // ---------------- Sweep A: per-lane min s per query (packed pairs) ----------------
    for (int c = 0; c < NCHUNK; ++c) {
        __syncthreads();
        for (int i = tid; i < CHUNK/2; i += BLOCK) {
            const float* p = pos_l + (size_t)(c * CHUNK + 2 * i) * 3;
            const f32x2 A = *(const f32x2*)(p + 0);   // x0 y0
            const f32x2 B = *(const f32x2*)(p + 2);   // z0 x1
            const f32x2 C = *(const f32x2*)(p + 4);   // y1 z1
            s_x[i] = (f32x2){A.x, B.y};
            s_y[i] = (f32x2){A.y, C.x};
            s_z[i] = (f32x2){B.x, C.y};
            s_w[i] = (f32x2){fmaf(A.x, A.x, fmaf(A.y, A.y, B.x * B.x)),
                             fmaf(B.y, B.y, fmaf(C.x, C.x, C.y * C.y))};
        }
        __syncthreads();
#pragma unroll
        for (int i = 0; i < CHUNK/128; ++i) {
            const int pi = i * 64 + lane;
            const f32x2 xp = s_x[pi], yp = s_y[pi], zp = s_z[pi], wp = s_w[pi];
#pragma unroll
            for (int j = 0; j < QPW/2; ++j) {
                f32x2 t0 = pk_fma_lo(xp, hxq[j], wp);
                t0 = pk_fma_lo(yp, hyq[j], t0);
                t0 = pk_fma_lo(zp, hzq[j], t0);
                rminp[2*j].x = fminf(rminp[2*j].x, t0.x);
                rminp[2*j].y = fminf(rminp[2*j].y, t0.y);
                f32x2 t1 = pk_fma_hi(xp, hxq[j], wp);
                t1 = pk_fma_hi(yp, hyq[j], t1);
                t1 = pk_fma_hi(zp, hzq[j], t1);
                rminp[2*j+1].x = fminf(rminp[2*j+1].x, t1.x);
                rminp[2*j+1].y = fminf(rminp[2*j+1].y, t1.y);
            }
        }
    }

    // --- tau = 32nd smallest of the 64 lane minima (bitonic, fp32, s-space) ---
    float tau_acc[QPW];
#pragma unroll
    for (int q = 0; q < QPW; ++q) {
        float v = fminf(rminp[q].x, rminp[q].y);
#pragma unroll
        for (int k = 2; k <= 64; k <<= 1) {
#pragma unroll
            for (int jj = k >> 1; jj >= 1; jj >>= 1) {
                const float o     = __shfl_xor(v, jj);
                const bool  up    = ((lane & k) == 0);
                const bool  lower = ((lane & jj) == 0);
                v = (lower == up) ? fminf(v, o) : fmaxf(v, o);
            }
        }
        // margin covers expansion-form fp32 rounding vs exact (same bound as d2-space:
        // s differs from d2 by an exact per-query constant shift)
        tau_acc[q] = __shfl(v, 31) + 1e-4f;
    }

    if (tid < QPB) s_cnt[tid] = 0;

    // ---------------- Sweep B: collect candidate indices with s <= tau ----------------
    for (int c = 0; c < NCHUNK; ++c) {
        __syncthreads();   // also publishes the counter reset on first iter
        for (int i = tid; i < CHUNK/2; i += BLOCK) {
            const float* p = pos_l + (size_t)(c * CHUNK + 2 * i) * 3;
            const f32x2 A = *(const f32x2*)(p + 0);
            const f32x2 B = *(const f32x2*)(p + 2);
            const f32x2 C = *(const f32x2*)(p + 4);
            s_x[i] = (f32x2){A.x, B.y};
            s_y[i] = (f32x2){A.y, C.x};
            s_z[i] = (f32x2){B.x, C.y};
            s_w[i] = (f32x2){fmaf(A.x, A.x, fmaf(A.y, A.y, B.x * B.x)),
                             fmaf(B.y, B.y, fmaf(C.x, C.x, C.y * C.y))};
        }
        __syncthreads();
#pragma unroll 2
        for (int i = 0; i < CHUNK/128; ++i) {
            const int pi = i * 64 + lane;
            const f32x2 xp = s_x[pi], yp = s_y[pi], zp = s_z[pi], wp = s_w[pi];
            const int g0 = c * CHUNK + 2 * pi;
#pragma unroll
            for (int j = 0; j < QPW/2; ++j) {
                f32x2 t0 = pk_fma_lo(xp, hxq[j], wp);
                t0 = pk_fma_lo(yp, hyq[j], t0);
                t0 = pk_fma_lo(zp, hzq[j], t0);
                f32x2 t1 = pk_fma_hi(xp, hxq[j], wp);
                t1 = pk_fma_hi(yp, hyq[j], t1);
                t1 = pk_fma_hi(zp, hzq[j], t1);
                const int q0 = wid * QPW + 2*j;
                if (t0.x <= tau_acc[2*j]) {
                    const uint32_t p0 = atomicAdd(&s_cnt[q0], 1u);
                    if (p0 < BUFCAP) s_idx[q0][p0] = (uint16_t)g0;
                }
                if (t0.y <= tau_acc[2*j]) {
                    const uint32_t p0 = atomicAdd(&s_cnt[q0], 1u);
                    if (p0 < BUFCAP) s_idx[q0][p0] = (uint16_t)(g0 + 1);
                }
                if (t1.x <= tau_acc[2*j+1]) {
                    const uint32_t p0 = atomicAdd(&s_cnt[q0 + 1], 1u);
                    if (p0 < BUFCAP) s_idx[q0 + 1][p0] = (uint16_t)g0;
                }
                if (t1.y <= tau_acc[2*j+1]) {
                    const uint32_t p0 = atomicAdd(&s_cnt[q0 + 1], 1u);
                    if (p0 < BUFCAP) s_idx[q0 + 1][p0] = (uint16_t)(g0 + 1);
                }
            }
        }
    }

    // ---- Final: exact fp64 re-rank of buffered candidates, pick top-32 ----
    // (s_cnt/s_idx/s_wd2/s_widx for query qq are private to wave wid; LDS ops
    //  within a wave are ordered, so no barrier is needed here.)
#pragma unroll 1
    for (int q = 0; q < QPW; ++q) {
        const int qq = wid * QPW + q;
        uint32_t M = s_cnt[qq];
        if (M > BUFCAP) M = BUFCAP;   // astronomically unlikely overflow

        // reload query coords from global (L2-hit) — avoids runtime-indexed
        // register arrays going to scratch
        const double axd = (double)pos_h[(size_t)(qbase + q) * 3 + 0];
        const double ayd = (double)pos_h[(size_t)(qbase + q) * 3 + 1];
        const double azd = (double)pos_h[(size_t)(qbase + q) * 3 + 2];

        const int i0 = ((uint32_t)(2 * lane)     < M) ? (int)s_idx[qq][2 * lane]     : -1;
        const int i1 = ((uint32_t)(2 * lane + 1) < M) ? (int)s_idx[qq][2 * lane + 1] : -1;
        float f0 = INFINITY, f1 = INFINITY;
        if (i0 >= 0) {
            const double dx = (double)pos_l[i0 * 3 + 0] - axd;
            const double dy = (double)pos_l[i0 * 3 + 1] - ayd;
            const double dz = (double)pos_l[i0 * 3 + 2] - azd;
            f0 = (float)(dx * dx + dy * dy + dz * dz);
        }
        if (i1 >= 0) {
            const double dx = (double)pos_l[i1 * 3 + 0] - axd;
            const double dy = (double)pos_l[i1 * 3 + 1] - ayd;
            const double dz = (double)pos_l[i1 * 3 + 2] - azd;
            f1 = (float)(dx * dx + dy * dy + dz * dz);
        }

        // bitonic-128 sort of d2 keys (int bits; d2 >= 0 so int order = float order)
        int v0 = __float_as_int(f0);
        int v1 = __float_as_int(f1);
#pragma unroll
        for (int k = 2; k <= 128; k <<= 1) {
            const bool up = ((lane & (k >> 1)) == 0);
#pragma unroll
            for (int j = k >> 1; j >= 2; j >>= 1) {
                const int  xo    = j >> 1;
                const bool lower = ((lane & xo) == 0);
                const int o0 = __shfl_xor(v0, xo);
                const int o1 = __shfl_xor(v1, xo);
                v0 = (lower == up) ? imin(v0, o0) : imax(v0, o0);
                v1 = (lower == up) ? imin(v1, o1) : imax(v1, o1);
            }
            const int mn = imin(v0, v1), mx = imax(v0, v1);  // j == 1 (in-lane)
            v0 = up ? mn : mx;
            v1 = up ? mx : mn;
        }
        // rank-31 element (32nd smallest) lives at element 31 = lane 15, slot v1
        const int tau32 = __shfl(v1, 15);

        // compact the winners (<= tau32) into s_wd2/s_widx via ballot prefix
        const bool a0 = (i0 >= 0) && (__float_as_int(f0) <= tau32);
        const bool a1 = (i1 >= 0) && (__float_as_int(f1) <= tau32);
        const unsigned long long b0 = __ballot(a0);
        const unsigned long long b1 = __ballot(a1);
        const unsigned long long mb = (lane == 63) ? 0x7FFFFFFFFFFFFFFFull
                                                   : ((1ull << (lane + 1)) - 1ull) >> 1;
        // mb = bits strictly below `lane`
        const int base = __popcll(b0 & mb) + __popcll(b1 & mb);
        const int p0 = base;
        const int p1 = base + (a0 ? 1 : 0);
        if (a0 && p0 < KSEL) { s_wd2[qq][p0] = f0; s_widx[qq][p0] = (uint16_t)i0; }
        if (a1 && p1 < KSEL) { s_wd2[qq][p1] = f1; s_widx[qq][p1] = (uint16_t)i1; }
    }

    // ---------------- gather + inverse-d2 weighted average (float2 lanes) ----------------
#pragma unroll 1
    for (int q = 0; q < QPW; ++q) {
        const int qq = wid * QPW + q;
        const int gq = qbase + q;
        f32x2 acc = (f32x2){0.0f, 0.0f};
        float wsum = 0.0f;
#pragma unroll 8
        for (int kk = 0; kk < KSEL; ++kk) {
            const float d2 = s_wd2[qq][kk];
            const float w  = __builtin_amdgcn_rcpf(fmaxf(d2, 1e-16f));  // ~1 ulp, well within tol
            const int  idx = (int)s_widx[qq][kk];
            const f32x2 r2 = *(const f32x2*)(x + (size_t)idx * FDIM + 2 * lane);
            acc.x = fmaf(w, r2.x, acc.x);
            acc.y = fmaf(w, r2.y, acc.y);
            wsum += w;
        }
        const float invw = __builtin_amdgcn_rcpf(wsum);
        *(f32x2*)(out + (size_t)gq * FDIM + 2 * lane) = (f32x2){acc.x * invw, acc.y * invw};
    }
}

extern "C" void kernel_launch(void* const* d_in, const int* in_sizes, int n_in,
                              void* d_out, int out_size, void* d_ws, size_t ws_size,
                              hipStream_t stream) {
    const float* x     = (const float*)d_in[0];
    const float* pos_l = (const float*)d_in[1];
    const float* pos_h = (const float*)d_in[2];
    float* out = (float*)d_out;
    dim3 grid(NH / QPB);
    dim3 block(BLOCK);
    hipLaunchKernelGGL(knn_interp_kernel, grid, block, 0, stream,
                       x, pos_l, pos_h, out);
}

// Round 2
// 178.743 us; speedup vs baseline: 1.0821x; 1.0195x over previous
//
#include <hip/hip_runtime.h>
#include <stdint.h>

#define NL     8192
#define NH     32768
#define FDIM   128
#define KSEL   32
#define CHUNK  1024
#define NCHUNK (NL / CHUNK)
#define QPW    4                 // queries per wave
#define NWAVES 8
#define BLOCK  (NWAVES * 64)     // 512 threads
#define QPB    (NWAVES * QPW)    // 32 queries per block
#define BUFCAP 128

typedef float f32x2 __attribute__((ext_vector_type(2)));

__device__ __forceinline__ int imin(int a, int b) { return a < b ? a : b; }
__device__ __forceinline__ int imax(int a, int b) { return a > b ? a : b; }

// Packed fp32 FMA, broadcasting src1's LOW register into both halves:
// d.lo = s0.lo * s1.lo + s2.lo ; d.hi = s0.hi * s1.lo + s2.hi
__device__ __forceinline__ f32x2 pk_fma_lo(f32x2 s0, f32x2 s1, f32x2 s2) {
    f32x2 d;
    asm("v_pk_fma_f32 %0, %1, %2, %3 op_sel:[0,0,0] op_sel_hi:[1,0,1]"
        : "=v"(d) : "v"(s0), "v"(s1), "v"(s2));
    return d;
}
// Packed fp32 FMA, broadcasting src1's HIGH register into both halves.
__device__ __forceinline__ f32x2 pk_fma_hi(f32x2 s0, f32x2 s1, f32x2 s2) {
    f32x2 d;
    asm("v_pk_fma_f32 %0, %1, %2, %3 op_sel:[0,1,0] op_sel_hi:[1,1,1]"
        : "=v"(d) : "v"(s0), "v"(s1), "v"(s2));
    return d;
}

__global__ __launch_bounds__(BLOCK, 8)   // 8 waves/EU -> 4 blocks/CU -> 32 waves/CU
void knn_interp_kernel(const float* __restrict__ x,
                       const float* __restrict__ pos_l,
                       const float* __restrict__ pos_h,
                       float* __restrict__ out)
{
    // SoA pair-packed candidate staging: element i holds candidates (2i, 2i+1)
    __shared__ f32x2    s_x[CHUNK/2], s_y[CHUNK/2], s_z[CHUNK/2], s_w[CHUNK/2]; // 16 KB
    __shared__ uint16_t s_idx[QPB][BUFCAP];     // 8 KB candidate index buffers
    __shared__ uint32_t s_cnt[QPB];
    __shared__ float    s_wd2[QPB][KSEL];       // 4 KB winner d2 (fp32 from fp64)
    __shared__ uint16_t s_widx[QPB][KSEL];      // 2 KB winner indices

    const int tid   = threadIdx.x;
    const int lane  = tid & 63;
    const int wid   = tid >> 6;
    const int qbase = blockIdx.x * QPB + wid * QPW;

    // per-query-pair packed params: hxq[j] = (-2*ax(2j), -2*ax(2j+1)), etc.
    // Sweeps rank by s = |l|^2 - 2 h.l  (= d2 - |h|^2, constant shift per query)
    f32x2 hxq[QPW/2], hyq[QPW/2], hzq[QPW/2];
#pragma unroll
    for (int j = 0; j < QPW/2; ++j) {
        const float a0x = pos_h[(size_t)(qbase + 2*j    ) * 3 + 0];
        const float a0y = pos_h[(size_t)(qbase + 2*j    ) * 3 + 1];
        const float a0z = pos_h[(size_t)(qbase + 2*j    ) * 3 + 2];
        const float a1x = pos_h[(size_t)(qbase + 2*j + 1) * 3 + 0];
        const float a1y = pos_h[(size_t)(qbase + 2*j + 1) * 3 + 1];
        const float a1z = pos_h[(size_t)(qbase + 2*j + 1) * 3 + 2];
        hxq[j] = (f32x2){-2.0f * a0x, -2.0f * a1x};
        hyq[j] = (f32x2){-2.0f * a0y, -2.0f * a1y};
        hzq[j] = (f32x2){-2.0f * a0z, -2.0f * a1z};
    }

    f32x2 rminp[QPW];
#pragma unroll
    for (int q = 0; q < QPW; ++q) rminp[q] = (f32x2){INFINITY, INFINITY};

    // ---------------- Sweep A: per-lane min s per query (packed pairs) ----------------
    for (int c = 0; c < NCHUNK; ++c) {
        __syncthreads();
        for (int i = tid; i < CHUNK/2; i += BLOCK) {
            const float* p = pos_l + (size_t)(c * CHUNK + 2 * i) * 3;
            const f32x2 A = *(const f32x2*)(p + 0);   // x0 y0
            const f32x2 B = *(const f32x2*)(p + 2);   // z0 x1
            const f32x2 C = *(const f32x2*)(p + 4);   // y1 z1
            s_x[i] = (f32x2){A.x, B.y};
            s_y[i] = (f32x2){A.y, C.x};
            s_z[i] = (f32x2){B.x, C.y};
            s_w[i] = (f32x2){fmaf(A.x, A.x, fmaf(A.y, A.y, B.x * B.x)),
                             fmaf(B.y, B.y, fmaf(C.x, C.x, C.y * C.y))};
        }
        __syncthreads();
#pragma unroll
        for (int i = 0; i < CHUNK/128; ++i) {
            const int pi = i * 64 + lane;
            const f32x2 xp = s_x[pi], yp = s_y[pi], zp = s_z[pi], wp = s_w[pi];
#pragma unroll
            for (int j = 0; j < QPW/2; ++j) {
                f32x2 t0 = pk_fma_lo(xp, hxq[j], wp);
                t0 = pk_fma_lo(yp, hyq[j], t0);
                t0 = pk_fma_lo(zp, hzq[j], t0);
                rminp[2*j].x = fminf(rminp[2*j].x, t0.x);
                rminp[2*j].y = fminf(rminp[2*j].y, t0.y);
                f32x2 t1 = pk_fma_hi(xp, hxq[j], wp);
                t1 = pk_fma_hi(yp, hyq[j], t1);
                t1 = pk_fma_hi(zp, hzq[j], t1);
                rminp[2*j+1].x = fminf(rminp[2*j+1].x, t1.x);
                rminp[2*j+1].y = fminf(rminp[2*j+1].y, t1.y);
            }
        }
    }

    // --- tau = 32nd smallest of the 64 lane minima (bitonic, fp32, s-space) ---
    float tau_acc[QPW];
#pragma unroll
    for (int q = 0; q < QPW; ++q) {
        float v = fminf(rminp[q].x, rminp[q].y);
#pragma unroll
        for (int k = 2; k <= 64; k <<= 1) {
#pragma unroll
            for (int jj = k >> 1; jj >= 1; jj >>= 1) {
                const float o     = __shfl_xor(v, jj);
                const bool  up    = ((lane & k) == 0);
                const bool  lower = ((lane & jj) == 0);
                v = (lower == up) ? fminf(v, o) : fmaxf(v, o);
            }
        }
        // margin covers expansion-form fp32 rounding vs exact (same bound as d2-space:
        // s differs from d2 by an exact per-query constant shift)
        tau_acc[q] = __shfl(v, 31) + 1e-4f;
    }

    if (tid < QPB) s_cnt[tid] = 0;

    // ---------------- Sweep B: collect candidate indices with s <= tau ----------------
    for (int c = 0; c < NCHUNK; ++c) {
        __syncthreads();   // also publishes the counter reset on first iter
        for (int i = tid; i < CHUNK/2; i += BLOCK) {
            const float* p = pos_l + (size_t)(c * CHUNK + 2 * i) * 3;
            const f32x2 A = *(const f32x2*)(p + 0);
            const f32x2 B = *(const f32x2*)(p + 2);
            const f32x2 C = *(const f32x2*)(p + 4);
            s_x[i] = (f32x2){A.x, B.y};
            s_y[i] = (f32x2){A.y, C.x};
            s_z[i] = (f32x2){B.x, C.y};
            s_w[i] = (f32x2){fmaf(A.x, A.x, fmaf(A.y, A.y, B.x * B.x)),
                             fmaf(B.y, B.y, fmaf(C.x, C.x, C.y * C.y))};
        }
        __syncthreads();
#pragma unroll 2
        for (int i = 0; i < CHUNK/128; ++i) {
            const int pi = i * 64 + lane;
            const f32x2 xp = s_x[pi], yp = s_y[pi], zp = s_z[pi], wp = s_w[pi];
            const int g0 = c * CHUNK + 2 * pi;
#pragma unroll
            for (int j = 0; j < QPW/2; ++j) {
                f32x2 t0 = pk_fma_lo(xp, hxq[j], wp);
                t0 = pk_fma_lo(yp, hyq[j], t0);
                t0 = pk_fma_lo(zp, hzq[j], t0);
                f32x2 t1 = pk_fma_hi(xp, hxq[j], wp);
                t1 = pk_fma_hi(yp, hyq[j], t1);
                t1 = pk_fma_hi(zp, hzq[j], t1);
                const int q0 = wid * QPW + 2*j;
                // wave-uniform skip: hits are ~0.8%/query/pair, gate once per query
                if (__any(fminf(t0.x, t0.y) <= tau_acc[2*j])) {
                    if (t0.x <= tau_acc[2*j]) {
                        const uint32_t p0 = atomicAdd(&s_cnt[q0], 1u);
                        if (p0 < BUFCAP) s_idx[q0][p0] = (uint16_t)g0;
                    }
                    if (t0.y <= tau_acc[2*j]) {
                        const uint32_t p0 = atomicAdd(&s_cnt[q0], 1u);
                        if (p0 < BUFCAP) s_idx[q0][p0] = (uint16_t)(g0 + 1);
                    }
                }
                if (__any(fminf(t1.x, t1.y) <= tau_acc[2*j+1])) {
                    if (t1.x <= tau_acc[2*j+1]) {
                        const uint32_t p0 = atomicAdd(&s_cnt[q0 + 1], 1u);
                        if (p0 < BUFCAP) s_idx[q0 + 1][p0] = (uint16_t)g0;
                    }
                    if (t1.y <= tau_acc[2*j+1]) {
                        const uint32_t p0 = atomicAdd(&s_cnt[q0 + 1], 1u);
                        if (p0 < BUFCAP) s_idx[q0 + 1][p0] = (uint16_t)(g0 + 1);
                    }
                }
            }
        }
    }

    // ---- Final: exact fp64 re-rank of buffered candidates, pick top-32 ----
    // (s_cnt/s_idx/s_wd2/s_widx for query qq are private to wave wid; LDS ops
    //  within a wave are ordered, so no barrier is needed here.)
#pragma unroll 1
    for (int q = 0; q < QPW; ++q) {
        const int qq = wid * QPW + q;
        uint32_t M = s_cnt[qq];
        if (M > BUFCAP) M = BUFCAP;   // astronomically unlikely overflow

        // reload query coords from global (L2-hit) — avoids runtime-indexed
        // register arrays going to scratch
        const double axd = (double)pos_h[(size_t)(qbase + q) * 3 + 0];
        const double ayd = (double)pos_h[(size_t)(qbase + q) * 3 + 1];
        const double azd = (double)pos_h[(size_t)(qbase + q) * 3 + 2];

        const int i0 = ((uint32_t)(2 * lane)     < M) ? (int)s_idx[qq][2 * lane]     : -1;
        const int i1 = ((uint32_t)(2 * lane + 1) < M) ? (int)s_idx[qq][2 * lane + 1] : -1;
        float f0 = INFINITY, f1 = INFINITY;
        if (i0 >= 0) {
            const double dx = (double)pos_l[i0 * 3 + 0] - axd;
            const double dy = (double)pos_l[i0 * 3 + 1] - ayd;
            const double dz = (double)pos_l[i0 * 3 + 2] - azd;
            f0 = (float)(dx * dx + dy * dy + dz * dz);
        }
        if (i1 >= 0) {
            const double dx = (double)pos_l[i1 * 3 + 0] - axd;
            const double dy = (double)pos_l[i1 * 3 + 1] - ayd;
            const double dz = (double)pos_l[i1 * 3 + 2] - azd;
            f1 = (float)(dx * dx + dy * dy + dz * dz);
        }

        // bitonic-128 sort of d2 keys (int bits; d2 >= 0 so int order = float order)
        int v0 = __float_as_int(f0);
        int v1 = __float_as_int(f1);
#pragma unroll
        for (int k = 2; k <= 128; k <<= 1) {
            const bool up = ((lane & (k >> 1)) == 0);
#pragma unroll
            for (int j = k >> 1; j >= 2; j >>= 1) {
                const int  xo    = j >> 1;
                const bool lower = ((lane & xo) == 0);
                const int o0 = __shfl_xor(v0, xo);
                const int o1 = __shfl_xor(v1, xo);
                v0 = (lower == up) ? imin(v0, o0) : imax(v0, o0);
                v1 = (lower == up) ? imin(v1, o1) : imax(v1, o1);
            }
            const int mn = imin(v0, v1), mx = imax(v0, v1);  // j == 1 (in-lane)
            v0 = up ? mn : mx;
            v1 = up ? mx : mn;
        }
        // rank-31 element (32nd smallest) lives at element 31 = lane 15, slot v1
        const int tau32 = __shfl(v1, 15);

        // compact the winners (<= tau32) into s_wd2/s_widx via ballot prefix
        const bool a0 = (i0 >= 0) && (__float_as_int(f0) <= tau32);
        const bool a1 = (i1 >= 0) && (__float_as_int(f1) <= tau32);
        const unsigned long long b0 = __ballot(a0);
        const unsigned long long b1 = __ballot(a1);
        const unsigned long long mb = (lane == 63) ? 0x7FFFFFFFFFFFFFFFull
                                                   : ((1ull << (lane + 1)) - 1ull) >> 1;
        // mb = bits strictly below `lane`
        const int base = __popcll(b0 & mb) + __popcll(b1 & mb);
        const int p0 = base;
        const int p1 = base + (a0 ? 1 : 0);
        if (a0 && p0 < KSEL) { s_wd2[qq][p0] = f0; s_widx[qq][p0] = (uint16_t)i0; }
        if (a1 && p1 < KSEL) { s_wd2[qq][p1] = f1; s_widx[qq][p1] = (uint16_t)i1; }
    }

    // ---------------- gather + inverse-d2 weighted average (float2 lanes) ----------------
#pragma unroll 1
    for (int q = 0; q < QPW; ++q) {
        const int qq = wid * QPW + q;
        const int gq = qbase + q;
        f32x2 acc = (f32x2){0.0f, 0.0f};
        float wsum = 0.0f;
#pragma unroll 8
        for (int kk = 0; kk < KSEL; ++kk) {
            const float d2 = s_wd2[qq][kk];
            const float w  = __builtin_amdgcn_rcpf(fmaxf(d2, 1e-16f));  // ~1 ulp, well within tol
            const int  idx = (int)s_widx[qq][kk];
            const f32x2 r2 = *(const f32x2*)(x + (size_t)idx * FDIM + 2 * lane);
            acc.x = fmaf(w, r2.x, acc.x);
            acc.y = fmaf(w, r2.y, acc.y);
            wsum += w;
        }
        const float invw = __builtin_amdgcn_rcpf(wsum);
        *(f32x2*)(out + (size_t)gq * FDIM + 2 * lane) = (f32x2){acc.x * invw, acc.y * invw};
    }
}

extern "C" void kernel_launch(void* const* d_in, const int* in_sizes, int n_in,
                              void* d_out, int out_size, void* d_ws, size_t ws_size,
                              hipStream_t stream) {
    const float* x     = (const float*)d_in[0];
    const float* pos_l = (const float*)d_in[1];
    const float* pos_h = (const float*)d_in[2];
    float* out = (float*)d_out;
    dim3 grid(NH / QPB);
    dim3 block(BLOCK);
    hipLaunchKernelGGL(knn_interp_kernel, grid, block, 0, stream,
                       x, pos_l, pos_h, out);
}